// Round 8
// baseline (857.491 us; speedup 1.0000x reference)
//
#include <hip/hip_runtime.h>
#include <math.h>

#define N_ 2048
#define NF_IN 64
#define D_ 256
#define H_ 8
#define HD_ 32
#define L_ 6
#define FFN_ 1024
#define E_ 32768
#define EF_ 16
#define NF 2049      // N+1 tokens (CLS at row 0)
#define MAXDEG_ 64
#define BSTRIDE 2112 // padded row stride: bytes for fp8 bias, shorts for Vt
#define RPAD 2112    // padded row count for attention partials
#define NSPLIT 4     // key splits for flash attention
#define APAD 264     // LDS A-tile row stride (shorts): 4-dword rotation/row

typedef __attribute__((ext_vector_type(8))) short bf16x8;
typedef __attribute__((ext_vector_type(4))) float f32x4;

__device__ inline unsigned short f2b(float f){
  union { float f; unsigned u; } v; v.f = f;
  unsigned r = (v.u + 0x7fffu + ((v.u >> 16) & 1u)) >> 16;
  return (unsigned short)r;
}

// manual OCP e4m3fn encode, RNE (prep-path only)
__device__ inline unsigned char f2fp8(float f){
  unsigned u = __float_as_uint(f);
  unsigned s = (u >> 24) & 0x80u;
  float a = fabsf(f);
  if (a >= 448.f) return (unsigned char)(s | 0x7Eu);
  if (a < 0.015625f){                      // denormal region (incl. 0)
    int k = (int)rintf(a * 512.f);         // step 2^-9; k=8 rolls into 2^-6
    return (unsigned char)(s | (unsigned)k);
  }
  int e; float m = frexpf(a, &e);          // a = m*2^e, m in [0.5,1)
  int E = e - 1;
  int m3 = (int)rintf(m * 16.f) - 8;       // 0..8
  if (m3 == 8){ E++; m3 = 0; }
  if (E > 8){ E = 8; m3 = 6; }
  if (E == 8 && m3 > 6) m3 = 6;
  return (unsigned char)(s | (unsigned)((E + 7) << 3) | (unsigned)m3);
}
__device__ inline float fp82f(unsigned char b){
  return __builtin_amdgcn_cvt_f32_fp8((int)b, 0);
}

__device__ inline void atomic_add_fp8(unsigned char* p, float add){
  unsigned* wp = (unsigned*)((size_t)p & ~(size_t)3);
  int sh = (int)((size_t)p & 3) * 8;
  unsigned old = *wp, assumed;
  do {
    assumed = old;
    unsigned char cur = (unsigned char)((assumed >> sh) & 0xFFu);
    float f = fp82f(cur) + add;
    unsigned nw = (assumed & ~(0xFFu << sh)) | ((unsigned)f2fp8(f) << sh);
    old = atomicCAS(wp, assumed, nw);
  } while (old != assumed);
}

__device__ inline float wred_sum(float v){
  #pragma unroll
  for (int o = 32; o > 0; o >>= 1) v += __shfl_down(v, o, 64);
  return v;
}

// LN of 64 rows of h into LDS A-tile (bf16, stride APAD).
// 256 threads: row = tid>>2 (4 lanes/row, contiguous lanes), seg = tid&3
// covering cols seg*64..seg*64+63. Two passes (stats, then normalize).
__device__ inline void ln_stage(const float* __restrict__ h, int bm,
                                const float* __restrict__ s,
                                const float* __restrict__ b,
                                short* __restrict__ As){
  const int tid = threadIdx.x;
  const int row = tid >> 2, seg = tid & 3;
  const int gm = bm + row;
  const float* hr = h + (long)gm * D_ + seg * 64;
  float s1 = 0.f, s2 = 0.f;
  if (gm < NF){
    #pragma unroll
    for (int k = 0; k < 16; k++){
      float4 v = *(const float4*)(hr + k * 4);
      s1 += v.x + v.y + v.z + v.w;
      s2 += v.x * v.x + v.y * v.y + v.z * v.z + v.w * v.w;
    }
  }
  s1 += __shfl_xor(s1, 1, 64); s1 += __shfl_xor(s1, 2, 64);
  s2 += __shfl_xor(s2, 1, 64); s2 += __shfl_xor(s2, 2, 64);
  float m = s1 * (1.0f / D_);
  float var = s2 * (1.0f / D_) - m * m;
  float rstd = rsqrtf(var + 1e-5f);
  short* dst = As + (long)row * APAD + seg * 64;
  if (gm < NF){
    #pragma unroll
    for (int k = 0; k < 8; k++){
      float4 v0 = *(const float4*)(hr + k * 8);
      float4 v1 = *(const float4*)(hr + k * 8 + 4);
      const float4 sc0 = *(const float4*)(s + seg * 64 + k * 8);
      const float4 sc1 = *(const float4*)(s + seg * 64 + k * 8 + 4);
      const float4 bi0 = *(const float4*)(b + seg * 64 + k * 8);
      const float4 bi1 = *(const float4*)(b + seg * 64 + k * 8 + 4);
      short o[8];
      o[0] = (short)f2b((v0.x - m) * rstd * sc0.x + bi0.x);
      o[1] = (short)f2b((v0.y - m) * rstd * sc0.y + bi0.y);
      o[2] = (short)f2b((v0.z - m) * rstd * sc0.z + bi0.z);
      o[3] = (short)f2b((v0.w - m) * rstd * sc0.w + bi0.w);
      o[4] = (short)f2b((v1.x - m) * rstd * sc1.x + bi1.x);
      o[5] = (short)f2b((v1.y - m) * rstd * sc1.y + bi1.y);
      o[6] = (short)f2b((v1.z - m) * rstd * sc1.z + bi1.z);
      o[7] = (short)f2b((v1.w - m) * rstd * sc1.w + bi1.w);
      *(bf16x8*)(dst + k * 8) = *(bf16x8*)o;
    }
  } else {
    #pragma unroll
    for (int k = 0; k < 8; k++){
      short o[8] = {0,0,0,0,0,0,0,0};
      *(bf16x8*)(dst + k * 8) = *(bf16x8*)o;
    }
  }
}

__global__ void zero_int(int* p, int n){
  int i = blockIdx.x * blockDim.x + threadIdx.x;
  if (i < n) p[i] = 0;
}

__global__ void deg_count(const int* __restrict__ ei, int* __restrict__ ind,
                          int* __restrict__ outd){
  int e = blockIdx.x * blockDim.x + threadIdx.x;
  if (e >= E_) return;
  atomicAdd(&outd[ei[e]], 1);
  atomicAdd(&ind[ei[E_ + e]], 1);
}

__global__ void embed_k(const float* __restrict__ x, const float* __restrict__ W,
                        const float* __restrict__ b, const float* __restrict__ inE,
                        const float* __restrict__ outE, const int* __restrict__ ind,
                        const int* __restrict__ outd, const float* __restrict__ cls,
                        float* __restrict__ h){
  int i = blockIdx.x, d = threadIdx.x;
  if (i == 0){ h[d] = cls[d]; return; }
  int n = i - 1;
  const float4* xr = (const float4*)(x + (long)n * NF_IN);
  const float4* wr = (const float4*)(W + (long)d * NF_IN);
  float acc = b[d];
  #pragma unroll
  for (int k = 0; k < NF_IN / 4; k++){
    float4 a = xr[k], w = wr[k];
    acc += a.x * w.x + a.y * w.y + a.z * w.z + a.w * w.w;
  }
  int id = min(ind[n], MAXDEG_), od = min(outd[n], MAXDEG_);
  acc += inE[(long)id * D_ + d] + outE[(long)od * D_ + d];
  h[(long)i * D_ + d] = acc;
}

// bias written directly as padded fp8 [h][i][j]; grid NF (one block per row i)
__global__ void bias_fill(const int* __restrict__ dist, const float* __restrict__ db,
                          unsigned char* __restrict__ bb){
  __shared__ unsigned char lut8[10][H_];
  int i = blockIdx.x;
  if (threadIdx.x < 80) ((unsigned char*)lut8)[threadIdx.x] = f2fp8(db[threadIdx.x]);
  __syncthreads();
  for (int u = threadIdx.x; u < BSTRIDE / 8; u += 256){
    int dp[8];
    #pragma unroll
    for (int k = 0; k < 8; k++){
      int j = u * 8 + k;
      int d = 0;
      if (i > 0 && j > 0 && j < NF){
        int dv = dist[(long)(i - 1) * N_ + (j - 1)];
        d = max(0, min(dv, 9));
      }
      dp[k] = (j < NF) ? d : -1;
    }
    #pragma unroll
    for (int h = 0; h < H_; h++){
      unsigned lo = 0, hi = 0;
      #pragma unroll
      for (int k = 0; k < 4; k++){
        unsigned b0 = (dp[k] >= 0) ? lut8[dp[k]][h] : 0u;
        unsigned b1 = (dp[4 + k] >= 0) ? lut8[dp[4 + k]][h] : 0u;
        lo |= b0 << (8 * k);
        hi |= b1 << (8 * k);
      }
      *(uint2*)(bb + ((long)h * NF + i) * BSTRIDE + u * 8) = make_uint2(lo, hi);
    }
  }
}

// sparse edge-feature bias: byte-CAS fp8 add into the dense bias planes
__global__ void edge_bias(const float* __restrict__ ea, const float* __restrict__ W,
                          const float* __restrict__ b, const int* __restrict__ ei,
                          unsigned char* __restrict__ bb){
  int e = blockIdx.x * blockDim.x + threadIdx.x;
  if (e >= E_) return;
  float a[EF_];
  #pragma unroll
  for (int k = 0; k < EF_; k++) a[k] = ea[(long)e * EF_ + k];
  int src = ei[e], dst = ei[E_ + e];
  #pragma unroll
  for (int h = 0; h < H_; h++){
    float p = b[h];
    #pragma unroll
    for (int k = 0; k < EF_; k++) p += a[k] * W[h * EF_ + k];
    atomic_add_fp8(bb + ((long)h * NF + src + 1) * BSTRIDE + (dst + 1), p);
  }
}

// all weight conversions in one dispatch
__global__ void w2b_all(const float* __restrict__ qw, const float* __restrict__ kw,
                        const float* __restrict__ vw, const float* __restrict__ ow,
                        const float* __restrict__ f1w, const float* __restrict__ f2w,
                        short* __restrict__ wqkv, short* __restrict__ owb,
                        short* __restrict__ f1wb, short* __restrict__ f2wb){
  long i = (long)blockIdx.x * 256 + threadIdx.x;
  const long DD = (long)D_ * D_, LDD = (long)L_ * DD, LFD = (long)L_ * FFN_ * D_;
  if (i < LDD){
    long l = i / DD, r = i - l * DD;
    wqkv[l * 3 * DD + r]          = (short)f2b(qw[i]);
    wqkv[l * 3 * DD + DD + r]     = (short)f2b(kw[i]);
    wqkv[l * 3 * DD + 2 * DD + r] = (short)f2b(vw[i]);
    owb[i] = (short)f2b(ow[i]);
  }
  if (i < LFD){
    f1wb[i] = (short)f2b(f1w[i]);
    f2wb[i] = (short)f2b(f2w[i]);
  }
}

// final LayerNorm (writes fp32 + duplicates row 0 at offset NF*D)
__global__ void ln_k(const float* __restrict__ in, const float* __restrict__ s,
                     const float* __restrict__ b, float* __restrict__ outf){
  __shared__ float r1[4], r2[4];
  int i = blockIdx.x, d = threadIdx.x;
  float v = in[(long)i * D_ + d];
  float s1 = wred_sum(v), s2 = wred_sum(v * v);
  if ((d & 63) == 0){ r1[d >> 6] = s1; r2[d >> 6] = s2; }
  __syncthreads();
  float S1 = r1[0] + r1[1] + r1[2] + r1[3];
  float S2 = r2[0] + r2[1] + r2[2] + r2[3];
  float m = S1 * (1.0f / D_);
  float var = S2 * (1.0f / D_) - m * m;
  float y = (v - m) * rsqrtf(var + 1e-5f) * s[d] + b[d];
  outf[(long)i * D_ + d] = y;
  if (i == 0) outf[(long)NF * D_ + d] = y;
}

// ---- fused LN + QKV MFMA GEMM: grid (33, 4, 3); z selects weight/output ----
__global__ __launch_bounds__(256) void qkv_gemm(const float* __restrict__ h,
    const float* __restrict__ lns, const float* __restrict__ lnb,
    const short* __restrict__ Wall, const float* __restrict__ qb,
    const float* __restrict__ kb, const float* __restrict__ vb,
    short* __restrict__ QKb, short* __restrict__ Vtg, int l){
  const int z = blockIdx.z;
  const short* W = Wall + ((long)(l * 3 + z)) * D_ * D_;
  const float* bsp = (z == 0) ? qb : (z == 1) ? kb : vb;
  __shared__ __align__(16) short As[64 * APAD];
  __shared__ __align__(16) short Ws[64][40];
  const int tid = threadIdx.x, lane = tid & 63, wave = tid >> 6;
  const int col = lane & 15, quad = lane >> 4;
  const int wm = wave & 1, wn = wave >> 1;
  const int bm = blockIdx.x * 64, bn = blockIdx.y * 64;
  const f32x4 zero4 = {0.f, 0.f, 0.f, 0.f};
  f32x4 acc[2][2] = {{zero4, zero4}, {zero4, zero4}};
  const int row = tid >> 2, seg = tid & 3;

  ln_stage(h, bm, lns, lnb, As);

  for (int k0 = 0; k0 < D_; k0 += 32){
    __syncthreads();
    *(bf16x8*)&Ws[row][seg * 8] = *(const bf16x8*)(W + (long)(bn + row) * D_ + k0 + seg * 8);
    __syncthreads();
    bf16x8 a0 = *(const bf16x8*)&As[(wm * 32 + col) * APAD + k0 + quad * 8];
    bf16x8 a1 = *(const bf16x8*)&As[(wm * 32 + 16 + col) * APAD + k0 + quad * 8];
    bf16x8 b0 = *(const bf16x8*)&Ws[wn * 32 + col][quad * 8];
    bf16x8 b1 = *(const bf16x8*)&Ws[wn * 32 + 16 + col][quad * 8];
    acc[0][0] = __builtin_amdgcn_mfma_f32_16x16x32_bf16(a0, b0, acc[0][0], 0, 0, 0);
    acc[0][1] = __builtin_amdgcn_mfma_f32_16x16x32_bf16(a0, b1, acc[0][1], 0, 0, 0);
    acc[1][0] = __builtin_amdgcn_mfma_f32_16x16x32_bf16(a1, b0, acc[1][0], 0, 0, 0);
    acc[1][1] = __builtin_amdgcn_mfma_f32_16x16x32_bf16(a1, b1, acc[1][1], 0, 0, 0);
  }
  #pragma unroll
  for (int i = 0; i < 2; i++)
    #pragma unroll
    for (int j = 0; j < 2; j++)
      #pragma unroll
      for (int r = 0; r < 4; r++){
        int gm = bm + wm * 32 + i * 16 + quad * 4 + r;
        if (gm >= NF) continue;
        int gn = bn + wn * 32 + j * 16 + col;
        float v = acc[i][j][r] + bsp[gn];
        if (z < 2) QKb[(long)z * NF * D_ + (long)gm * D_ + gn] = (short)f2b(v);
        else       Vtg[(long)gn * BSTRIDE + gm] = (short)f2b(v);
      }
}

// ---- fused LN + FFN1 GEMM (gelu, bf16 out): grid (33, 16) ----
__global__ __launch_bounds__(256) void f1_gemm(const float* __restrict__ h,
    const float* __restrict__ lns, const float* __restrict__ lnb,
    const short* __restrict__ W, const float* __restrict__ bs,
    short* __restrict__ Cb){
  __shared__ __align__(16) short As[64 * APAD];
  __shared__ __align__(16) short Ws[64][40];
  const int tid = threadIdx.x, lane = tid & 63, wave = tid >> 6;
  const int col = lane & 15, quad = lane >> 4;
  const int wm = wave & 1, wn = wave >> 1;
  const int bm = blockIdx.x * 64, bn = blockIdx.y * 64;
  const f32x4 zero4 = {0.f, 0.f, 0.f, 0.f};
  f32x4 acc[2][2] = {{zero4, zero4}, {zero4, zero4}};
  const int row = tid >> 2, seg = tid & 3;

  ln_stage(h, bm, lns, lnb, As);

  for (int k0 = 0; k0 < D_; k0 += 32){
    __syncthreads();
    *(bf16x8*)&Ws[row][seg * 8] = *(const bf16x8*)(W + (long)(bn + row) * D_ + k0 + seg * 8);
    __syncthreads();
    bf16x8 a0 = *(const bf16x8*)&As[(wm * 32 + col) * APAD + k0 + quad * 8];
    bf16x8 a1 = *(const bf16x8*)&As[(wm * 32 + 16 + col) * APAD + k0 + quad * 8];
    bf16x8 b0 = *(const bf16x8*)&Ws[wn * 32 + col][quad * 8];
    bf16x8 b1 = *(const bf16x8*)&Ws[wn * 32 + 16 + col][quad * 8];
    acc[0][0] = __builtin_amdgcn_mfma_f32_16x16x32_bf16(a0, b0, acc[0][0], 0, 0, 0);
    acc[0][1] = __builtin_amdgcn_mfma_f32_16x16x32_bf16(a0, b1, acc[0][1], 0, 0, 0);
    acc[1][0] = __builtin_amdgcn_mfma_f32_16x16x32_bf16(a1, b0, acc[1][0], 0, 0, 0);
    acc[1][1] = __builtin_amdgcn_mfma_f32_16x16x32_bf16(a1, b1, acc[1][1], 0, 0, 0);
  }
  #pragma unroll
  for (int i = 0; i < 2; i++)
    #pragma unroll
    for (int j = 0; j < 2; j++)
      #pragma unroll
      for (int r = 0; r < 4; r++){
        int gm = bm + wm * 32 + i * 16 + quad * 4 + r;
        if (gm >= NF) continue;
        int gn = bn + wn * 32 + j * 16 + col;
        float v = acc[i][j][r] + bs[gn];
        v = v * 0.5f * (1.0f + erff(v * 0.70710678118654752f));
        Cb[(long)gm * FFN_ + gn] = (short)f2b(v);
      }
}

// ---- generic MFMA GEMM (o-proj merge / FFN2).
// MERGE=1: A[gm][k] = (sum_q Opart[q][k/32][gm][k%32]) / (sum_q Lpart[q][k/32][gm])
// atomicAdd partial into Cf (bias added by z==0 block).
template<int MERGE>
__global__ __launch_bounds__(256) void mgemm(const short* __restrict__ A,
    const float* __restrict__ Op, const float* __restrict__ Lp,
    const short* __restrict__ W, const float* __restrict__ bs,
    float* __restrict__ Cf, int M, int Nn, int Kc, int Kstride){
  __shared__ __align__(16) short As[64][40], Ws[64][40];
  const int tid = threadIdx.x, lane = tid & 63, wave = tid >> 6;
  const int col = lane & 15, quad = lane >> 4;
  const int wm = wave & 1, wn = wave >> 1;
  const int bm = blockIdx.x * 64, bn = blockIdx.y * 64;
  const int koff = blockIdx.z * Kc;
  const f32x4 zero4 = {0.f, 0.f, 0.f, 0.f};
  f32x4 acc[2][2] = {{zero4, zero4}, {zero4, zero4}};
  const int row = tid >> 2, seg = tid & 3;
  for (int k0 = 0; k0 < Kc; k0 += 32){
    __syncthreads();
    int gm = bm + row;
    if (MERGE){
      int kg = koff + k0 + seg * 8;
      int hh = kg >> 5, d0 = kg & 31;
      short sarr[8] = {0,0,0,0,0,0,0,0};
      if (gm < M){
        float o0=0,o1=0,o2=0,o3=0,o4=0,o5=0,o6=0,o7=0, sl=0.f;
        #pragma unroll
        for (int q = 0; q < NSPLIT; q++){
          long rb = (long)(q * H_ + hh) * RPAD + gm;
          const float* op = Op + rb * HD_ + d0;
          float4 v0 = *(const float4*)op, v1 = *(const float4*)(op + 4);
          o0 += v0.x; o1 += v0.y; o2 += v0.z; o3 += v0.w;
          o4 += v1.x; o5 += v1.y; o6 += v1.z; o7 += v1.w;
          sl += Lp[rb];
        }
        float inv = 1.0f / sl;
        sarr[0]=(short)f2b(o0*inv); sarr[1]=(short)f2b(o1*inv);
        sarr[2]=(short)f2b(o2*inv); sarr[3]=(short)f2b(o3*inv);
        sarr[4]=(short)f2b(o4*inv); sarr[5]=(short)f2b(o5*inv);
        sarr[6]=(short)f2b(o6*inv); sarr[7]=(short)f2b(o7*inv);
      }
      *(bf16x8*)&As[row][seg * 8] = *(bf16x8*)sarr;
    } else {
      bf16x8 av = (bf16x8)(short)0;
      if (gm < M) av = *(const bf16x8*)(A + (long)gm * Kstride + koff + k0 + seg * 8);
      *(bf16x8*)&As[row][seg * 8] = av;
    }
    *(bf16x8*)&Ws[row][seg * 8] =
      *(const bf16x8*)(W + (long)(bn + row) * Kstride + koff + k0 + seg * 8);
    __syncthreads();
    bf16x8 a0 = *(const bf16x8*)&As[wm * 32 + col][quad * 8];
    bf16x8 a1 = *(const bf16x8*)&As[wm * 32 + 16 + col][quad * 8];
    bf16x8 b0 = *(const bf16x8*)&Ws[wn * 32 + col][quad * 8];
    bf16x8 b1 = *(const bf16x8*)&Ws[wn * 32 + 16 + col][quad * 8];
    acc[0][0] = __builtin_amdgcn_mfma_f32_16x16x32_bf16(a0, b0, acc[0][0], 0, 0, 0);
    acc[0][1] = __builtin_amdgcn_mfma_f32_16x16x32_bf16(a0, b1, acc[0][1], 0, 0, 0);
    acc[1][0] = __builtin_amdgcn_mfma_f32_16x16x32_bf16(a1, b0, acc[1][0], 0, 0, 0);
    acc[1][1] = __builtin_amdgcn_mfma_f32_16x16x32_bf16(a1, b1, acc[1][1], 0, 0, 0);
  }
  #pragma unroll
  for (int i = 0; i < 2; i++)
    #pragma unroll
    for (int j = 0; j < 2; j++)
      #pragma unroll
      for (int r = 0; r < 4; r++){
        int gm = bm + wm * 32 + i * 16 + quad * 4 + r;
        if (gm >= M) continue;
        int gn = bn + wn * 32 + j * 16 + col;
        float v = acc[i][j][r] + (blockIdx.z == 0 ? bs[gn] : 0.f);
        atomicAdd(&Cf[(long)gm * Nn + gn], v);
      }
}

// ---- flash attention, fixed-shift softmax, fp8 bias.
// grid (33, H, NSPLIT); block = 4 waves x 16 rows. fp8 bias bytes staged into
// the per-wave PS buffer (stride 80B), logits buffered in sacc registers, then
// the SAME buffer holds P as bf16 (stride 72 shorts).
__global__ __launch_bounds__(256) void fattn_k(const short* __restrict__ Qb,
    const short* __restrict__ Kb, const short* __restrict__ Vtg,
    const unsigned char* __restrict__ bias8, float* __restrict__ Opart,
    float* __restrict__ Lpart){
  __shared__ __align__(16) short Ks[64][40];
  __shared__ __align__(16) short Vt[32][72];
  __shared__ __align__(16) unsigned char PS[4][2304];

  const int tid = threadIdx.x, wave = tid >> 6, lane = tid & 63;
  const int col = lane & 15, quad = lane >> 4;
  const int h = blockIdx.y, qz = blockIdx.z;
  const int i0 = blockIdx.x * 64 + wave * 16;
  const int t0 = (qz == 0) ? 0 : 9 + 8 * (qz - 1);   // 0,9,17,25
  const int t1 = t0 + ((qz == 0) ? 9 : 8);           // 33 tiles total

  int qrow = min(i0 + col, NF - 1);
  bf16x8 qf = *(const bf16x8*)(Qb + (long)qrow * D_ + h * HD_ + quad * 8);

  f32x4 oacc0 = {0.f, 0.f, 0.f, 0.f}, oacc1 = {0.f, 0.f, 0.f, 0.f};
  float rs[4] = {0.f, 0.f, 0.f, 0.f};
  const f32x4 zero4 = {0.f, 0.f, 0.f, 0.f};
  const float scale = 0.17677669529663687f;  // 1/sqrt(32)
  short* Pp = (short*)PS[wave];

  for (int t = t0; t < t1; t++){
    const int j0 = t * 64;
    __syncthreads();
    { // K tile: 64 keys x 32 dims
      int key = tid >> 2, seg = tid & 3;
      int j = j0 + key;
      bf16x8 kv = (bf16x8)(short)0;
      if (j < NF) kv = *(const bf16x8*)(Kb + (long)j * D_ + h * HD_ + seg * 8);
      *(bf16x8*)&Ks[key][seg * 8] = kv;
    }
    { // V tile (pre-transposed): 32 dims x 64 keys
      int d = tid >> 3, seg = tid & 7;
      *(bf16x8*)&Vt[d][seg * 8] =
        *(const bf16x8*)(Vtg + (long)(h * HD_ + d) * BSTRIDE + j0 + seg * 8);
    }
    { // per-wave fp8 bias tile: 16 rows x 64 bytes, LDS stride 80
      int rw = lane >> 2, seg = lane & 3;
      int irow = min(i0 + rw, NF - 1);
      uint4 bv = *(const uint4*)(bias8 + (long)(h * NF + irow) * BSTRIDE + j0 + seg * 16);
      uint2* d2 = (uint2*)&PS[wave][rw * 80 + seg * 16];
      d2[0] = make_uint2(bv.x, bv.y);
      d2[1] = make_uint2(bv.z, bv.w);
    }
    __syncthreads();

    f32x4 sacc[4];
    #pragma unroll
    for (int t4 = 0; t4 < 4; t4++){
      bf16x8 kf = *(const bf16x8*)&Ks[t4 * 16 + col][quad * 8];
      sacc[t4] = __builtin_amdgcn_mfma_f32_16x16x32_bf16(qf, kf, zero4, 0, 0, 0);
    }

    const bool tail = (j0 + 64 > NF);
    #pragma unroll
    for (int r = 0; r < 4; r++){
      #pragma unroll
      for (int t4 = 0; t4 < 4; t4++){
        float bv = fp82f(PS[wave][(quad * 4 + r) * 80 + t4 * 16 + col]);
        float p = __expf(sacc[t4][r] * scale + bv);
        if (tail && (j0 + t4 * 16 + col >= NF)) p = 0.f;
        rs[r] += p;
        sacc[t4][r] = p;              // buffer in regs: all bias reads done
      }
    }
    #pragma unroll
    for (int r = 0; r < 4; r++)
      #pragma unroll
      for (int t4 = 0; t4 < 4; t4++)
        Pp[(quad * 4 + r) * 72 + t4 * 16 + col] = (short)f2b(sacc[t4][r]);

    #pragma unroll
    for (int ks = 0; ks < 2; ks++){
      bf16x8 af = *(const bf16x8*)&Pp[col * 72 + ks * 32 + quad * 8];
      bf16x8 v0 = *(const bf16x8*)&Vt[col][ks * 32 + quad * 8];
      bf16x8 v1 = *(const bf16x8*)&Vt[16 + col][ks * 32 + quad * 8];
      oacc0 = __builtin_amdgcn_mfma_f32_16x16x32_bf16(af, v0, oacc0, 0, 0, 0);
      oacc1 = __builtin_amdgcn_mfma_f32_16x16x32_bf16(af, v1, oacc1, 0, 0, 0);
    }
  }

  #pragma unroll
  for (int r = 0; r < 4; r++){
    #pragma unroll
    for (int o = 1; o < 16; o <<= 1) rs[r] += __shfl_xor(rs[r], o, 64);
  }
  long pi = ((long)qz * H_ + h) * RPAD + i0 + quad * 4;
  #pragma unroll
  for (int r = 0; r < 4; r++){
    Opart[(pi + r) * HD_ + col] = oacc0[r];
    Opart[(pi + r) * HD_ + 16 + col] = oacc1[r];
    if (col == 0) Lpart[pi + r] = rs[r];
  }
}

extern "C" void kernel_launch(void* const* d_in, const int* in_sizes, int n_in,
                              void* d_out, int out_size, void* d_ws, size_t ws_size,
                              hipStream_t stream){
  const float* x    = (const float*)d_in[0];
  const float* ea   = (const float*)d_in[1];
  const float* npw  = (const float*)d_in[2];
  const float* npb  = (const float*)d_in[3];
  const float* inE  = (const float*)d_in[4];
  const float* outE = (const float*)d_in[5];
  const float* db   = (const float*)d_in[6];
  const float* epw  = (const float*)d_in[7];
  const float* epb  = (const float*)d_in[8];
  const float* cls  = (const float*)d_in[9];
  const float* qw   = (const float*)d_in[10];
  const float* qb   = (const float*)d_in[11];
  const float* kw   = (const float*)d_in[12];
  const float* kb   = (const float*)d_in[13];
  const float* vw   = (const float*)d_in[14];
  const float* vb   = (const float*)d_in[15];
  const float* ow   = (const float*)d_in[16];
  const float* ob   = (const float*)d_in[17];
  const float* f1w  = (const float*)d_in[18];
  const float* f1b  = (const float*)d_in[19];
  const float* f2w  = (const float*)d_in[20];
  const float* f2bp = (const float*)d_in[21];
  const float* ln1s = (const float*)d_in[22];
  const float* ln1b = (const float*)d_in[23];
  const float* ln2s = (const float*)d_in[24];
  const float* ln2b = (const float*)d_in[25];
  const float* fns  = (const float*)d_in[26];
  const float* fnb  = (const float*)d_in[27];
  const int*   ei   = (const int*)d_in[28];
  const int*   dist = (const int*)d_in[29];

  float* ws = (float*)d_ws;
  long off = 0;
  float* h     = ws + off; off += (long)NF * D_;
  float* Opart = ws + off; off += (long)NSPLIT * H_ * RPAD * HD_;
  float* Lpart = ws + off; off += (long)NSPLIT * H_ * RPAD;
  unsigned char* bias8 = (unsigned char*)(ws + off);
  off += ((long)H_ * NF * BSTRIDE + 3) / 4;
  short* QKb   = (short*)(ws + off); off += (long)NF * D_;      // Q then K
  short* Vtg   = (short*)(ws + off); off += ((long)D_ * BSTRIDE + 1) / 2;
  short* midb  = (short*)(ws + off); off += ((long)NF * FFN_ + 1) / 2;
  short* wqkv  = (short*)(ws + off); off += ((long)3 * L_ * D_ * D_ + 1) / 2;
  short* owb   = (short*)(ws + off); off += ((long)L_ * D_ * D_ + 1) / 2;
  short* f1wb  = (short*)(ws + off); off += ((long)L_ * FFN_ * D_ + 1) / 2;
  short* f2wb  = (short*)(ws + off); off += ((long)L_ * FFN_ * D_ + 1) / 2;
  int*   ind   = (int*)(ws + off);
  int*   outd  = ind + N_;

  zero_int<<<(2 * N_ + 255) / 256, 256, 0, stream>>>(ind, 2 * N_);
  deg_count<<<(E_ + 255) / 256, 256, 0, stream>>>(ei, ind, outd);
  embed_k<<<NF, D_, 0, stream>>>(x, npw, npb, inE, outE, ind, outd, cls, h);
  bias_fill<<<NF, 256, 0, stream>>>(dist, db, bias8);
  edge_bias<<<(E_ + 255) / 256, 256, 0, stream>>>(ea, epw, epb, ei, bias8);
  {
    long LFD = (long)L_ * FFN_ * D_;
    w2b_all<<<(int)((LFD + 255) / 256), 256, 0, stream>>>(qw, kw, vw, ow, f1w, f2w,
                                                          wqkv, owb, f1wb, f2wb);
  }

  dim3 gQKV((NF + 63) / 64, D_ / 64, 3);
  dim3 gO((NF + 63) / 64, D_ / 64, 2);
  dim3 gF((NF + 63) / 64, FFN_ / 64);
  dim3 gF2((NF + 63) / 64, D_ / 64, 4);
  dim3 gA((NF + 63) / 64, H_, NSPLIT);
  for (int l = 0; l < L_; l++){
    qkv_gemm<<<gQKV, 256, 0, stream>>>(h, ln1s + l * D_, ln1b + l * D_, wqkv,
                                       qb + l * D_, kb + l * D_, vb + l * D_,
                                       QKb, Vtg, l);
    fattn_k<<<gA, 256, 0, stream>>>(QKb, QKb + (long)NF * D_, Vtg, bias8, Opart, Lpart);
    mgemm<1><<<gO, 256, 0, stream>>>(nullptr, Opart, Lpart,
                                     owb + (long)l * D_ * D_, ob + l * D_,
                                     h, NF, D_, 128, D_);
    f1_gemm<<<gF, 256, 0, stream>>>(h, ln2s + l * D_, ln2b + l * D_,
                                    f1wb + (long)l * FFN_ * D_, f1b + l * FFN_, midb);
    mgemm<0><<<gF2, 256, 0, stream>>>(midb, nullptr, nullptr,
                                      f2wb + (long)l * FFN_ * D_, f2bp + l * D_,
                                      h, NF, D_, 256, FFN_);
  }
  ln_k<<<NF, D_, 0, stream>>>(h, fns, fnb, (float*)d_out);
}

// Round 10
// 692.256 us; speedup vs baseline: 1.2387x; 1.2387x over previous
//
#include <hip/hip_runtime.h>
#include <math.h>

#define N_ 2048
#define NF_IN 64
#define D_ 256
#define H_ 8
#define HD_ 32
#define L_ 6
#define FFN_ 1024
#define E_ 32768
#define EF_ 16
#define NF 2049      // N+1 tokens (CLS at row 0)
#define MAXDEG_ 64
#define BSTRIDE 2112 // padded row stride: bytes for fp8 bias, shorts for Vt
#define RPAD 2112    // padded row count for attention partials
#define NSPLIT 4     // key splits for flash attention
#define LOG2E 1.4426950408889634f

typedef __attribute__((ext_vector_type(8))) short bf16x8;
typedef __attribute__((ext_vector_type(4))) float f32x4;

__device__ inline unsigned short f2b(float f){
  union { float f; unsigned u; } v; v.f = f;
  unsigned r = (v.u + 0x7fffu + ((v.u >> 16) & 1u)) >> 16;
  return (unsigned short)r;
}
__device__ inline float b2f(short s){
  union { unsigned u; float f; } v; v.u = ((unsigned)(unsigned short)s) << 16;
  return v.f;
}

// manual OCP e4m3fn encode, RNE (prep-path only)
__device__ inline unsigned char f2fp8(float f){
  unsigned u = __float_as_uint(f);
  unsigned s = (u >> 24) & 0x80u;
  float a = fabsf(f);
  if (a >= 448.f) return (unsigned char)(s | 0x7Eu);
  if (a < 0.015625f){                      // denormal region (incl. 0)
    int k = (int)rintf(a * 512.f);         // step 2^-9; k=8 rolls into 2^-6
    return (unsigned char)(s | (unsigned)k);
  }
  int e; float m = frexpf(a, &e);          // a = m*2^e, m in [0.5,1)
  int E = e - 1;
  int m3 = (int)rintf(m * 16.f) - 8;       // 0..8
  if (m3 == 8){ E++; m3 = 0; }
  if (E > 8){ E = 8; m3 = 6; }
  if (E == 8 && m3 > 6) m3 = 6;
  return (unsigned char)(s | (unsigned)((E + 7) << 3) | (unsigned)m3);
}
__device__ inline float fp82f(unsigned char b){
  return __builtin_amdgcn_cvt_f32_fp8((int)b, 0);
}

__device__ inline void atomic_add_fp8(unsigned char* p, float add){
  unsigned* wp = (unsigned*)((size_t)p & ~(size_t)3);
  int sh = (int)((size_t)p & 3) * 8;
  unsigned old = *wp, assumed;
  do {
    assumed = old;
    unsigned char cur = (unsigned char)((assumed >> sh) & 0xFFu);
    float f = fp82f(cur) + add;
    unsigned nw = (assumed & ~(0xFFu << sh)) | ((unsigned)f2fp8(f) << sh);
    old = atomicCAS(wp, assumed, nw);
  } while (old != assumed);
}

__device__ inline float wred_sum(float v){
  #pragma unroll
  for (int o = 32; o > 0; o >>= 1) v += __shfl_down(v, o, 64);
  return v;
}

__global__ void zero_int(int* p, int n){
  int i = blockIdx.x * blockDim.x + threadIdx.x;
  if (i < n) p[i] = 0;
}

__global__ void deg_count(const int* __restrict__ ei, int* __restrict__ ind,
                          int* __restrict__ outd){
  int e = blockIdx.x * blockDim.x + threadIdx.x;
  if (e >= E_) return;
  atomicAdd(&outd[ei[e]], 1);
  atomicAdd(&ind[ei[E_ + e]], 1);
}

__global__ void embed_k(const float* __restrict__ x, const float* __restrict__ W,
                        const float* __restrict__ b, const float* __restrict__ inE,
                        const float* __restrict__ outE, const int* __restrict__ ind,
                        const int* __restrict__ outd, const float* __restrict__ cls,
                        float* __restrict__ h){
  int i = blockIdx.x, d = threadIdx.x;
  if (i == 0){ h[d] = cls[d]; return; }
  int n = i - 1;
  const float4* xr = (const float4*)(x + (long)n * NF_IN);
  const float4* wr = (const float4*)(W + (long)d * NF_IN);
  float acc = b[d];
  #pragma unroll
  for (int k = 0; k < NF_IN / 4; k++){
    float4 a = xr[k], w = wr[k];
    acc += a.x * w.x + a.y * w.y + a.z * w.z + a.w * w.w;
  }
  int id = min(ind[n], MAXDEG_), od = min(outd[n], MAXDEG_);
  acc += inE[(long)id * D_ + d] + outE[(long)od * D_ + d];
  h[(long)i * D_ + d] = acc;
}

// bias stored as fp8 of (bias * log2e) — exp2-domain; grid NF
__global__ void bias_fill(const int* __restrict__ dist, const float* __restrict__ db,
                          unsigned char* __restrict__ bb){
  __shared__ unsigned char lut8[10][H_];
  int i = blockIdx.x;
  if (threadIdx.x < 80)
    ((unsigned char*)lut8)[threadIdx.x] = f2fp8(db[threadIdx.x] * LOG2E);
  __syncthreads();
  for (int u = threadIdx.x; u < BSTRIDE / 8; u += 256){
    int dp[8];
    #pragma unroll
    for (int k = 0; k < 8; k++){
      int j = u * 8 + k;
      int d = 0;
      if (i > 0 && j > 0 && j < NF){
        int dv = dist[(long)(i - 1) * N_ + (j - 1)];
        d = max(0, min(dv, 9));
      }
      dp[k] = (j < NF) ? d : -1;
    }
    #pragma unroll
    for (int h = 0; h < H_; h++){
      unsigned lo = 0, hi = 0;
      #pragma unroll
      for (int k = 0; k < 4; k++){
        unsigned b0 = (dp[k] >= 0) ? lut8[dp[k]][h] : 0u;
        unsigned b1 = (dp[4 + k] >= 0) ? lut8[dp[4 + k]][h] : 0u;
        lo |= b0 << (8 * k);
        hi |= b1 << (8 * k);
      }
      *(uint2*)(bb + ((long)h * NF + i) * BSTRIDE + u * 8) = make_uint2(lo, hi);
    }
  }
}

// sparse edge-feature bias: byte-CAS fp8 add (also log2e-scaled)
__global__ void edge_bias(const float* __restrict__ ea, const float* __restrict__ W,
                          const float* __restrict__ b, const int* __restrict__ ei,
                          unsigned char* __restrict__ bb){
  int e = blockIdx.x * blockDim.x + threadIdx.x;
  if (e >= E_) return;
  float a[EF_];
  #pragma unroll
  for (int k = 0; k < EF_; k++) a[k] = ea[(long)e * EF_ + k];
  int src = ei[e], dst = ei[E_ + e];
  #pragma unroll
  for (int h = 0; h < H_; h++){
    float p = b[h];
    #pragma unroll
    for (int k = 0; k < EF_; k++) p += a[k] * W[h * EF_ + k];
    atomic_add_fp8(bb + ((long)h * NF + src + 1) * BSTRIDE + (dst + 1), p * LOG2E);
  }
}

// all weight conversions in one dispatch
__global__ void w2b_all(const float* __restrict__ qw, const float* __restrict__ kw,
                        const float* __restrict__ vw, const float* __restrict__ ow,
                        const float* __restrict__ f1w, const float* __restrict__ f2w,
                        short* __restrict__ wqkv, short* __restrict__ owb,
                        short* __restrict__ f1wb, short* __restrict__ f2wb){
  long i = (long)blockIdx.x * 256 + threadIdx.x;
  const long DD = (long)D_ * D_, LDD = (long)L_ * DD, LFD = (long)L_ * FFN_ * D_;
  if (i < LDD){
    long l = i / DD, r = i - l * DD;
    wqkv[l * 3 * DD + r]          = (short)f2b(qw[i]);
    wqkv[l * 3 * DD + DD + r]     = (short)f2b(kw[i]);
    wqkv[l * 3 * DD + 2 * DD + r] = (short)f2b(vw[i]);
    owb[i] = (short)f2b(ow[i]);
  }
  if (i < LFD){
    f1wb[i] = (short)f2b(f1w[i]);
    f2wb[i] = (short)f2b(f2w[i]);
  }
}

__global__ void ln_k(const float* __restrict__ in, const float* __restrict__ s,
                     const float* __restrict__ b, float* __restrict__ outf,
                     short* __restrict__ outb, int dup0){
  __shared__ float r1[4], r2[4];
  int i = blockIdx.x, d = threadIdx.x;
  float v = in[(long)i * D_ + d];
  float s1 = wred_sum(v), s2 = wred_sum(v * v);
  if ((d & 63) == 0){ r1[d >> 6] = s1; r2[d >> 6] = s2; }
  __syncthreads();
  float S1 = r1[0] + r1[1] + r1[2] + r1[3];
  float S2 = r2[0] + r2[1] + r2[2] + r2[3];
  float m = S1 * (1.0f / D_);
  float var = S2 * (1.0f / D_) - m * m;
  float y = (v - m) * rsqrtf(var + 1e-5f) * s[d] + b[d];
  if (outf){
    outf[(long)i * D_ + d] = y;
    if (dup0 && i == 0) outf[(long)NF * D_ + d] = y;
  }
  if (outb) outb[(long)i * D_ + d] = (short)f2b(y);
}

// ---- fused QKV MFMA GEMM: grid (33, 4, 3). z==0 (Q) is pre-scaled by
// (1/sqrt(HD))*log2e so fattn's softmax works in the exp2 domain.
__global__ __launch_bounds__(256) void qkv_gemm(const short* __restrict__ A,
    const short* __restrict__ Wall, const float* __restrict__ qb,
    const float* __restrict__ kb, const float* __restrict__ vb,
    short* __restrict__ QKb, short* __restrict__ Vtg, int l){
  const int z = blockIdx.z;
  const short* W = Wall + ((long)(l * 3 + z)) * D_ * D_;
  const float* bsp = (z == 0) ? qb : (z == 1) ? kb : vb;
  __shared__ __align__(16) short As[64][40], Ws[64][40];
  const int tid = threadIdx.x, lane = tid & 63, wave = tid >> 6;
  const int col = lane & 15, quad = lane >> 4;
  const int wm = wave & 1, wn = wave >> 1;
  const int bm = blockIdx.x * 64, bn = blockIdx.y * 64;
  const f32x4 zero4 = {0.f, 0.f, 0.f, 0.f};
  f32x4 acc[2][2] = {{zero4, zero4}, {zero4, zero4}};
  const int row = tid >> 2, seg = tid & 3;
  for (int k0 = 0; k0 < D_; k0 += 32){
    __syncthreads();
    bf16x8 av = (bf16x8)(short)0;
    int gm = bm + row;
    if (gm < NF) av = *(const bf16x8*)(A + (long)gm * D_ + k0 + seg * 8);
    *(bf16x8*)&As[row][seg * 8] = av;
    *(bf16x8*)&Ws[row][seg * 8] = *(const bf16x8*)(W + (long)(bn + row) * D_ + k0 + seg * 8);
    __syncthreads();
    bf16x8 a0 = *(const bf16x8*)&As[wm * 32 + col][quad * 8];
    bf16x8 a1 = *(const bf16x8*)&As[wm * 32 + 16 + col][quad * 8];
    bf16x8 b0 = *(const bf16x8*)&Ws[wn * 32 + col][quad * 8];
    bf16x8 b1 = *(const bf16x8*)&Ws[wn * 32 + 16 + col][quad * 8];
    acc[0][0] = __builtin_amdgcn_mfma_f32_16x16x32_bf16(a0, b0, acc[0][0], 0, 0, 0);
    acc[0][1] = __builtin_amdgcn_mfma_f32_16x16x32_bf16(a0, b1, acc[0][1], 0, 0, 0);
    acc[1][0] = __builtin_amdgcn_mfma_f32_16x16x32_bf16(a1, b0, acc[1][0], 0, 0, 0);
    acc[1][1] = __builtin_amdgcn_mfma_f32_16x16x32_bf16(a1, b1, acc[1][1], 0, 0, 0);
  }
  const float qscale = 0.25501133194822025f;  // (1/sqrt(32)) * log2e
  #pragma unroll
  for (int i = 0; i < 2; i++)
    #pragma unroll
    for (int j = 0; j < 2; j++)
      #pragma unroll
      for (int r = 0; r < 4; r++){
        int gm = bm + wm * 32 + i * 16 + quad * 4 + r;
        if (gm >= NF) continue;
        int gn = bn + wn * 32 + j * 16 + col;
        float v = acc[i][j][r] + bsp[gn];
        if (z == 0) v *= qscale;
        if (z < 2) QKb[(long)z * NF * D_ + (long)gm * D_ + gn] = (short)f2b(v);
        else       Vtg[(long)gn * BSTRIDE + gm] = (short)f2b(v);
      }
}

// ---- generic MFMA GEMM.
// MERGE=1: A[gm][k] = (sum_q Opart[q][k/32][gm][k%32]) / (sum_q Lpart[q][k/32][gm])
// ATOM=1: atomicAdd partial into Cf (bias added by z==0 block); else bf16 out + ACT.
template<int ACT, int ATOM, int MERGE>
__global__ __launch_bounds__(256) void mgemm(const short* __restrict__ A,
    const float* __restrict__ Op, const float* __restrict__ Lp,
    const short* __restrict__ W, const float* __restrict__ bs,
    float* __restrict__ Cf, short* __restrict__ Cb,
    int M, int Nn, int Kc, int Kstride){
  __shared__ __align__(16) short As[64][40], Ws[64][40];
  const int tid = threadIdx.x, lane = tid & 63, wave = tid >> 6;
  const int col = lane & 15, quad = lane >> 4;
  const int wm = wave & 1, wn = wave >> 1;
  const int bm = blockIdx.x * 64, bn = blockIdx.y * 64;
  const int koff = blockIdx.z * Kc;
  const f32x4 zero4 = {0.f, 0.f, 0.f, 0.f};
  f32x4 acc[2][2] = {{zero4, zero4}, {zero4, zero4}};
  const int row = tid >> 2, seg = tid & 3;
  for (int k0 = 0; k0 < Kc; k0 += 32){
    __syncthreads();
    int gm = bm + row;
    if (MERGE){
      int kg = koff + k0 + seg * 8;
      int hh = kg >> 5, d0 = kg & 31;
      short sarr[8] = {0,0,0,0,0,0,0,0};
      if (gm < M){
        float o0=0,o1=0,o2=0,o3=0,o4=0,o5=0,o6=0,o7=0, sl=0.f;
        #pragma unroll
        for (int q = 0; q < NSPLIT; q++){
          long rb = (long)(q * H_ + hh) * RPAD + gm;
          const float* op = Op + rb * HD_ + d0;
          float4 v0 = *(const float4*)op, v1 = *(const float4*)(op + 4);
          o0 += v0.x; o1 += v0.y; o2 += v0.z; o3 += v0.w;
          o4 += v1.x; o5 += v1.y; o6 += v1.z; o7 += v1.w;
          sl += Lp[rb];
        }
        float inv = 1.0f / sl;
        sarr[0]=(short)f2b(o0*inv); sarr[1]=(short)f2b(o1*inv);
        sarr[2]=(short)f2b(o2*inv); sarr[3]=(short)f2b(o3*inv);
        sarr[4]=(short)f2b(o4*inv); sarr[5]=(short)f2b(o5*inv);
        sarr[6]=(short)f2b(o6*inv); sarr[7]=(short)f2b(o7*inv);
      }
      *(bf16x8*)&As[row][seg * 8] = *(bf16x8*)sarr;
    } else {
      bf16x8 av = (bf16x8)(short)0;
      if (gm < M) av = *(const bf16x8*)(A + (long)gm * Kstride + koff + k0 + seg * 8);
      *(bf16x8*)&As[row][seg * 8] = av;
    }
    *(bf16x8*)&Ws[row][seg * 8] =
      *(const bf16x8*)(W + (long)(bn + row) * Kstride + koff + k0 + seg * 8);
    __syncthreads();
    bf16x8 a0 = *(const bf16x8*)&As[wm * 32 + col][quad * 8];
    bf16x8 a1 = *(const bf16x8*)&As[wm * 32 + 16 + col][quad * 8];
    bf16x8 b0 = *(const bf16x8*)&Ws[wn * 32 + col][quad * 8];
    bf16x8 b1 = *(const bf16x8*)&Ws[wn * 32 + 16 + col][quad * 8];
    acc[0][0] = __builtin_amdgcn_mfma_f32_16x16x32_bf16(a0, b0, acc[0][0], 0, 0, 0);
    acc[0][1] = __builtin_amdgcn_mfma_f32_16x16x32_bf16(a0, b1, acc[0][1], 0, 0, 0);
    acc[1][0] = __builtin_amdgcn_mfma_f32_16x16x32_bf16(a1, b0, acc[1][0], 0, 0, 0);
    acc[1][1] = __builtin_amdgcn_mfma_f32_16x16x32_bf16(a1, b1, acc[1][1], 0, 0, 0);
  }
  #pragma unroll
  for (int i = 0; i < 2; i++)
    #pragma unroll
    for (int j = 0; j < 2; j++)
      #pragma unroll
      for (int r = 0; r < 4; r++){
        int gm = bm + wm * 32 + i * 16 + quad * 4 + r;
        if (gm >= M) continue;
        int gn = bn + wn * 32 + j * 16 + col;
        if (ATOM){
          float v = acc[i][j][r] + (blockIdx.z == 0 ? bs[gn] : 0.f);
          atomicAdd(&Cf[(long)gm * Nn + gn], v);
        } else {
          float v = acc[i][j][r] + bs[gn];
          if (ACT == 1) v = v * 0.5f * (1.0f + erff(v * 0.70710678118654752f));
          Cb[(long)gm * Nn + gn] = (short)f2b(v);
        }
      }
}

// ---- flash attention, fixed-shift softmax in exp2 domain.
// grid (33, H, NSPLIT); block = 4 waves x 16 rows.
// Key permutation: MFMA sub-tile t4 covers key j0 + col*4 + t4, so each lane's
// 4 bias bytes per row are ONE coalesced global dword (no LDS staging, no
// scalar byte reads), and P is written with 4 packed ds_write_b64 per tile.
__global__ __launch_bounds__(256) void fattn_k(const short* __restrict__ Qb,
    const short* __restrict__ Kb, const short* __restrict__ Vtg,
    const unsigned char* __restrict__ bias8, float* __restrict__ Opart,
    float* __restrict__ Lpart){
  __shared__ __align__(16) short Ks[64][42];   // stride 42: 2-way max on permuted reads
  __shared__ __align__(16) short Vt[32][72];
  __shared__ __align__(16) short Ps[4][16][72];

  const int tid = threadIdx.x, wave = tid >> 6, lane = tid & 63;
  const int col = lane & 15, quad = lane >> 4;
  const int h = blockIdx.y, qz = blockIdx.z;
  const int i0 = blockIdx.x * 64 + wave * 16;
  const int t0 = (qz == 0) ? 0 : 9 + 8 * (qz - 1);   // 0,9,17,25
  const int t1 = t0 + ((qz == 0) ? 9 : 8);           // 33 tiles total

  int qrow = min(i0 + col, NF - 1);
  bf16x8 qf = *(const bf16x8*)(Qb + (long)qrow * D_ + h * HD_ + quad * 8);

  int brow[4];
  #pragma unroll
  for (int r = 0; r < 4; r++) brow[r] = min(i0 + quad * 4 + r, NF - 1);

  f32x4 oacc0 = {0.f, 0.f, 0.f, 0.f}, oacc1 = {0.f, 0.f, 0.f, 0.f};
  float rs[4] = {0.f, 0.f, 0.f, 0.f};
  const f32x4 zero4 = {0.f, 0.f, 0.f, 0.f};
  short* Pp = &Ps[wave][0][0];

  for (int t = t0; t < t1; t++){
    const int j0 = t * 64;
    // bias: one dword per row (4 fp8 bytes for t4=0..3), coalesced across col
    unsigned bw[4];
    #pragma unroll
    for (int r = 0; r < 4; r++)
      bw[r] = *(const unsigned*)(bias8 + (long)(h * NF + brow[r]) * BSTRIDE + j0 + col * 4);
    __syncthreads();
    { // K tile: 64 keys x 32 dims
      int key = tid >> 2, seg = tid & 3;
      int j = j0 + key;
      bf16x8 kv = (bf16x8)(short)0;
      if (j < NF) kv = *(const bf16x8*)(Kb + (long)j * D_ + h * HD_ + seg * 8);
      *(bf16x8*)&Ks[key][seg * 8] = kv;
    }
    { // V tile (pre-transposed): 32 dims x 64 keys
      int d = tid >> 3, seg = tid & 7;
      *(bf16x8*)&Vt[d][seg * 8] =
        *(const bf16x8*)(Vtg + (long)(h * HD_ + d) * BSTRIDE + j0 + seg * 8);
    }
    __syncthreads();

    f32x4 sacc[4];
    #pragma unroll
    for (int t4 = 0; t4 < 4; t4++){
      bf16x8 kf = *(const bf16x8*)&Ks[col * 4 + t4][quad * 8];
      sacc[t4] = __builtin_amdgcn_mfma_f32_16x16x32_bf16(qf, kf, zero4, 0, 0, 0);
    }

    const bool tail = (j0 + 64 > NF);
    #pragma unroll
    for (int r = 0; r < 4; r++){
      // fp8 byte-select must be a literal: decode all 4 bytes explicitly
      float bv0 = __builtin_amdgcn_cvt_f32_fp8((int)bw[r], 0);
      float bv1 = __builtin_amdgcn_cvt_f32_fp8((int)bw[r], 1);
      float bv2 = __builtin_amdgcn_cvt_f32_fp8((int)bw[r], 2);
      float bv3 = __builtin_amdgcn_cvt_f32_fp8((int)bw[r], 3);
      float bvv[4] = {bv0, bv1, bv2, bv3};
      unsigned short pb[4];
      #pragma unroll
      for (int t4 = 0; t4 < 4; t4++){
        float p = exp2f(sacc[t4][r] + bvv[t4]);   // Q pre-scaled by scale*log2e
        if (tail && (j0 + col * 4 + t4 >= NF)) p = 0.f;
        unsigned pu = __float_as_uint(p) & 0xffff0000u;  // RTZ to bf16
        rs[r] += __uint_as_float(pu);                    // consistent with PV
        pb[t4] = (unsigned short)(pu >> 16);
      }
      unsigned u0 = (unsigned)pb[0] | ((unsigned)pb[1] << 16);
      unsigned u1 = (unsigned)pb[2] | ((unsigned)pb[3] << 16);
      *(uint2*)&Pp[(quad * 4 + r) * 72 + col * 4] = make_uint2(u0, u1);
    }

    #pragma unroll
    for (int ks = 0; ks < 2; ks++){
      bf16x8 af = *(const bf16x8*)&Pp[col * 72 + ks * 32 + quad * 8];
      bf16x8 v0 = *(const bf16x8*)&Vt[col][ks * 32 + quad * 8];
      bf16x8 v1 = *(const bf16x8*)&Vt[16 + col][ks * 32 + quad * 8];
      oacc0 = __builtin_amdgcn_mfma_f32_16x16x32_bf16(af, v0, oacc0, 0, 0, 0);
      oacc1 = __builtin_amdgcn_mfma_f32_16x16x32_bf16(af, v1, oacc1, 0, 0, 0);
    }
  }

  #pragma unroll
  for (int r = 0; r < 4; r++){
    #pragma unroll
    for (int o = 1; o < 16; o <<= 1) rs[r] += __shfl_xor(rs[r], o, 64);
  }
  long pi = ((long)qz * H_ + h) * RPAD + i0 + quad * 4;
  #pragma unroll
  for (int r = 0; r < 4; r++){
    Opart[(pi + r) * HD_ + col] = oacc0[r];
    Opart[(pi + r) * HD_ + 16 + col] = oacc1[r];
    if (col == 0) Lpart[pi + r] = rs[r];
  }
}

extern "C" void kernel_launch(void* const* d_in, const int* in_sizes, int n_in,
                              void* d_out, int out_size, void* d_ws, size_t ws_size,
                              hipStream_t stream){
  const float* x    = (const float*)d_in[0];
  const float* ea   = (const float*)d_in[1];
  const float* npw  = (const float*)d_in[2];
  const float* npb  = (const float*)d_in[3];
  const float* inE  = (const float*)d_in[4];
  const float* outE = (const float*)d_in[5];
  const float* db   = (const float*)d_in[6];
  const float* epw  = (const float*)d_in[7];
  const float* epb  = (const float*)d_in[8];
  const float* cls  = (const float*)d_in[9];
  const float* qw   = (const float*)d_in[10];
  const float* qb   = (const float*)d_in[11];
  const float* kw   = (const float*)d_in[12];
  const float* kb   = (const float*)d_in[13];
  const float* vw   = (const float*)d_in[14];
  const float* vb   = (const float*)d_in[15];
  const float* ow   = (const float*)d_in[16];
  const float* ob   = (const float*)d_in[17];
  const float* f1w  = (const float*)d_in[18];
  const float* f1b  = (const float*)d_in[19];
  const float* f2w  = (const float*)d_in[20];
  const float* f2bp = (const float*)d_in[21];
  const float* ln1s = (const float*)d_in[22];
  const float* ln1b = (const float*)d_in[23];
  const float* ln2s = (const float*)d_in[24];
  const float* ln2b = (const float*)d_in[25];
  const float* fns  = (const float*)d_in[26];
  const float* fnb  = (const float*)d_in[27];
  const int*   ei   = (const int*)d_in[28];
  const int*   dist = (const int*)d_in[29];

  float* ws = (float*)d_ws;
  long off = 0;
  float* h     = ws + off; off += (long)NF * D_;
  float* Opart = ws + off; off += (long)NSPLIT * H_ * RPAD * HD_;
  float* Lpart = ws + off; off += (long)NSPLIT * H_ * RPAD;
  unsigned char* bias8 = (unsigned char*)(ws + off);
  off += ((long)H_ * NF * BSTRIDE + 3) / 4;
  short* hnb   = (short*)(ws + off); off += ((long)NF * D_ + 1) / 2;
  short* QKb   = (short*)(ws + off); off += (long)NF * D_;      // Q then K
  short* Vtg   = (short*)(ws + off); off += ((long)D_ * BSTRIDE + 1) / 2;
  short* midb  = (short*)(ws + off); off += ((long)NF * FFN_ + 1) / 2;
  short* wqkv  = (short*)(ws + off); off += ((long)3 * L_ * D_ * D_ + 1) / 2;
  short* owb   = (short*)(ws + off); off += ((long)L_ * D_ * D_ + 1) / 2;
  short* f1wb  = (short*)(ws + off); off += ((long)L_ * FFN_ * D_ + 1) / 2;
  short* f2wb  = (short*)(ws + off); off += ((long)L_ * FFN_ * D_ + 1) / 2;
  int*   ind   = (int*)(ws + off);
  int*   outd  = ind + N_;

  zero_int<<<(2 * N_ + 255) / 256, 256, 0, stream>>>(ind, 2 * N_);
  deg_count<<<(E_ + 255) / 256, 256, 0, stream>>>(ei, ind, outd);
  embed_k<<<NF, D_, 0, stream>>>(x, npw, npb, inE, outE, ind, outd, cls, h);
  bias_fill<<<NF, 256, 0, stream>>>(dist, db, bias8);
  edge_bias<<<(E_ + 255) / 256, 256, 0, stream>>>(ea, epw, epb, ei, bias8);
  {
    long LFD = (long)L_ * FFN_ * D_;
    w2b_all<<<(int)((LFD + 255) / 256), 256, 0, stream>>>(qw, kw, vw, ow, f1w, f2w,
                                                          wqkv, owb, f1wb, f2wb);
  }

  dim3 gQKV((NF + 63) / 64, D_ / 64, 3);
  dim3 gO((NF + 63) / 64, D_ / 64, 2);
  dim3 gF((NF + 63) / 64, FFN_ / 64, 1);
  dim3 gF2((NF + 63) / 64, D_ / 64, 4);
  dim3 gA((NF + 63) / 64, H_, NSPLIT);
  for (int l = 0; l < L_; l++){
    ln_k<<<NF, D_, 0, stream>>>(h, ln1s + l * D_, ln1b + l * D_, nullptr, hnb, 0);
    qkv_gemm<<<gQKV, 256, 0, stream>>>(hnb, wqkv, qb + l * D_, kb + l * D_, vb + l * D_,
                                       QKb, Vtg, l);
    fattn_k<<<gA, 256, 0, stream>>>(QKb, QKb + (long)NF * D_, Vtg, bias8, Opart, Lpart);
    mgemm<0,1,1><<<gO, 256, 0, stream>>>(nullptr, Opart, Lpart,
                                         owb + (long)l * D_ * D_, ob + l * D_,
                                         h, nullptr, NF, D_, 128, D_);
    ln_k<<<NF, D_, 0, stream>>>(h, ln2s + l * D_, ln2b + l * D_, nullptr, hnb, 0);
    mgemm<1,0,0><<<gF, 256, 0, stream>>>(hnb, nullptr, nullptr,
                                         f1wb + (long)l * FFN_ * D_, f1b + l * FFN_,
                                         nullptr, midb, NF, FFN_, D_, D_);
    mgemm<0,1,0><<<gF2, 256, 0, stream>>>(midb, nullptr, nullptr,
                                          f2wb + (long)l * FFN_ * D_, f2bp + l * D_,
                                          h, nullptr, NF, D_, 256, FFN_);
  }
  ln_k<<<NF, D_, 0, stream>>>(h, fns, fnb, (float*)d_out, nullptr, 1);
}

// Round 11
// 683.374 us; speedup vs baseline: 1.2548x; 1.0130x over previous
//
#include <hip/hip_runtime.h>
#include <math.h>

#define N_ 2048
#define NF_IN 64
#define D_ 256
#define H_ 8
#define HD_ 32
#define L_ 6
#define FFN_ 1024
#define E_ 32768
#define EF_ 16
#define NF 2049      // N+1 tokens (CLS at row 0)
#define MAXDEG_ 64
#define BSTRIDE 2112 // padded row stride: bytes for fp8 bias, shorts for Vt
#define RPAD 2112    // padded row count for attention partials
#define NSPLIT 4     // key splits for flash attention
#define LOG2E 1.4426950408889634f

typedef __attribute__((ext_vector_type(8))) short bf16x8;
typedef __attribute__((ext_vector_type(4))) float f32x4;

__device__ inline unsigned short f2b(float f){
  union { float f; unsigned u; } v; v.f = f;
  unsigned r = (v.u + 0x7fffu + ((v.u >> 16) & 1u)) >> 16;
  return (unsigned short)r;
}
__device__ inline float b2f(short s){
  union { unsigned u; float f; } v; v.u = ((unsigned)(unsigned short)s) << 16;
  return v.f;
}

// manual OCP e4m3fn encode, RNE (prep-path only)
__device__ inline unsigned char f2fp8(float f){
  unsigned u = __float_as_uint(f);
  unsigned s = (u >> 24) & 0x80u;
  float a = fabsf(f);
  if (a >= 448.f) return (unsigned char)(s | 0x7Eu);
  if (a < 0.015625f){                      // denormal region (incl. 0)
    int k = (int)rintf(a * 512.f);         // step 2^-9; k=8 rolls into 2^-6
    return (unsigned char)(s | (unsigned)k);
  }
  int e; float m = frexpf(a, &e);          // a = m*2^e, m in [0.5,1)
  int E = e - 1;
  int m3 = (int)rintf(m * 16.f) - 8;       // 0..8
  if (m3 == 8){ E++; m3 = 0; }
  if (E > 8){ E = 8; m3 = 6; }
  if (E == 8 && m3 > 6) m3 = 6;
  return (unsigned char)(s | (unsigned)((E + 7) << 3) | (unsigned)m3);
}
__device__ inline float fp82f(unsigned char b){
  return __builtin_amdgcn_cvt_f32_fp8((int)b, 0);
}

__device__ inline void atomic_add_fp8(unsigned char* p, float add){
  unsigned* wp = (unsigned*)((size_t)p & ~(size_t)3);
  int sh = (int)((size_t)p & 3) * 8;
  unsigned old = *wp, assumed;
  do {
    assumed = old;
    unsigned char cur = (unsigned char)((assumed >> sh) & 0xFFu);
    float f = fp82f(cur) + add;
    unsigned nw = (assumed & ~(0xFFu << sh)) | ((unsigned)f2fp8(f) << sh);
    old = atomicCAS(wp, assumed, nw);
  } while (old != assumed);
}

__device__ inline float wred_sum(float v){
  #pragma unroll
  for (int o = 32; o > 0; o >>= 1) v += __shfl_down(v, o, 64);
  return v;
}

__global__ void zero_int(int* p, int n){
  int i = blockIdx.x * blockDim.x + threadIdx.x;
  if (i < n) p[i] = 0;
}

__global__ void deg_count(const int* __restrict__ ei, int* __restrict__ ind,
                          int* __restrict__ outd){
  int e = blockIdx.x * blockDim.x + threadIdx.x;
  if (e >= E_) return;
  atomicAdd(&outd[ei[e]], 1);
  atomicAdd(&ind[ei[E_ + e]], 1);
}

__global__ void embed_k(const float* __restrict__ x, const float* __restrict__ W,
                        const float* __restrict__ b, const float* __restrict__ inE,
                        const float* __restrict__ outE, const int* __restrict__ ind,
                        const int* __restrict__ outd, const float* __restrict__ cls,
                        float* __restrict__ h){
  int i = blockIdx.x, d = threadIdx.x;
  if (i == 0){ h[d] = cls[d]; return; }
  int n = i - 1;
  const float4* xr = (const float4*)(x + (long)n * NF_IN);
  const float4* wr = (const float4*)(W + (long)d * NF_IN);
  float acc = b[d];
  #pragma unroll
  for (int k = 0; k < NF_IN / 4; k++){
    float4 a = xr[k], w = wr[k];
    acc += a.x * w.x + a.y * w.y + a.z * w.z + a.w * w.w;
  }
  int id = min(ind[n], MAXDEG_), od = min(outd[n], MAXDEG_);
  acc += inE[(long)id * D_ + d] + outE[(long)od * D_ + d];
  h[(long)i * D_ + d] = acc;
}

// bias stored as fp8 of (bias * log2e) — exp2-domain; grid NF
__global__ void bias_fill(const int* __restrict__ dist, const float* __restrict__ db,
                          unsigned char* __restrict__ bb){
  __shared__ unsigned char lut8[10][H_];
  int i = blockIdx.x;
  if (threadIdx.x < 80)
    ((unsigned char*)lut8)[threadIdx.x] = f2fp8(db[threadIdx.x] * LOG2E);
  __syncthreads();
  for (int u = threadIdx.x; u < BSTRIDE / 8; u += 256){
    int dp[8];
    #pragma unroll
    for (int k = 0; k < 8; k++){
      int j = u * 8 + k;
      int d = 0;
      if (i > 0 && j > 0 && j < NF){
        int dv = dist[(long)(i - 1) * N_ + (j - 1)];
        d = max(0, min(dv, 9));
      }
      dp[k] = (j < NF) ? d : -1;
    }
    #pragma unroll
    for (int h = 0; h < H_; h++){
      unsigned lo = 0, hi = 0;
      #pragma unroll
      for (int k = 0; k < 4; k++){
        unsigned b0 = (dp[k] >= 0) ? lut8[dp[k]][h] : 0u;
        unsigned b1 = (dp[4 + k] >= 0) ? lut8[dp[4 + k]][h] : 0u;
        lo |= b0 << (8 * k);
        hi |= b1 << (8 * k);
      }
      *(uint2*)(bb + ((long)h * NF + i) * BSTRIDE + u * 8) = make_uint2(lo, hi);
    }
  }
}

// sparse edge-feature bias: byte-CAS fp8 add (also log2e-scaled)
__global__ void edge_bias(const float* __restrict__ ea, const float* __restrict__ W,
                          const float* __restrict__ b, const int* __restrict__ ei,
                          unsigned char* __restrict__ bb){
  int e = blockIdx.x * blockDim.x + threadIdx.x;
  if (e >= E_) return;
  float a[EF_];
  #pragma unroll
  for (int k = 0; k < EF_; k++) a[k] = ea[(long)e * EF_ + k];
  int src = ei[e], dst = ei[E_ + e];
  #pragma unroll
  for (int h = 0; h < H_; h++){
    float p = b[h];
    #pragma unroll
    for (int k = 0; k < EF_; k++) p += a[k] * W[h * EF_ + k];
    atomic_add_fp8(bb + ((long)h * NF + src + 1) * BSTRIDE + (dst + 1), p * LOG2E);
  }
}

// all weight conversions in one dispatch
__global__ void w2b_all(const float* __restrict__ qw, const float* __restrict__ kw,
                        const float* __restrict__ vw, const float* __restrict__ ow,
                        const float* __restrict__ f1w, const float* __restrict__ f2w,
                        short* __restrict__ wqkv, short* __restrict__ owb,
                        short* __restrict__ f1wb, short* __restrict__ f2wb){
  long i = (long)blockIdx.x * 256 + threadIdx.x;
  const long DD = (long)D_ * D_, LDD = (long)L_ * DD, LFD = (long)L_ * FFN_ * D_;
  if (i < LDD){
    long l = i / DD, r = i - l * DD;
    wqkv[l * 3 * DD + r]          = (short)f2b(qw[i]);
    wqkv[l * 3 * DD + DD + r]     = (short)f2b(kw[i]);
    wqkv[l * 3 * DD + 2 * DD + r] = (short)f2b(vw[i]);
    owb[i] = (short)f2b(ow[i]);
  }
  if (i < LFD){
    f1wb[i] = (short)f2b(f1w[i]);
    f2wb[i] = (short)f2b(f2w[i]);
  }
}

__global__ void ln_k(const float* __restrict__ in, const float* __restrict__ s,
                     const float* __restrict__ b, float* __restrict__ outf,
                     short* __restrict__ outb, int dup0){
  __shared__ float r1[4], r2[4];
  int i = blockIdx.x, d = threadIdx.x;
  float v = in[(long)i * D_ + d];
  float s1 = wred_sum(v), s2 = wred_sum(v * v);
  if ((d & 63) == 0){ r1[d >> 6] = s1; r2[d >> 6] = s2; }
  __syncthreads();
  float S1 = r1[0] + r1[1] + r1[2] + r1[3];
  float S2 = r2[0] + r2[1] + r2[2] + r2[3];
  float m = S1 * (1.0f / D_);
  float var = S2 * (1.0f / D_) - m * m;
  float y = (v - m) * rsqrtf(var + 1e-5f) * s[d] + b[d];
  if (outf){
    outf[(long)i * D_ + d] = y;
    if (dup0 && i == 0) outf[(long)NF * D_ + d] = y;
  }
  if (outb) outb[(long)i * D_ + d] = (short)f2b(y);
}

// ---- fused QKV MFMA GEMM: grid (33, 4, 3). z==0 (Q) is pre-scaled by
// (1/sqrt(HD))*log2e so fattn's softmax works in the exp2 domain.
// z==2 (V): epilogue transposes the 64x64 tile through LDS so Vtg rows are
// written with coalesced 128B segments (the old per-lane scatter touched
// 64 cache lines per store instruction).
__global__ __launch_bounds__(256) void qkv_gemm(const short* __restrict__ A,
    const short* __restrict__ Wall, const float* __restrict__ qb,
    const float* __restrict__ kb, const float* __restrict__ vb,
    short* __restrict__ QKb, short* __restrict__ Vtg, int l){
  const int z = blockIdx.z;
  const short* W = Wall + ((long)(l * 3 + z)) * D_ * D_;
  const float* bsp = (z == 0) ? qb : (z == 1) ? kb : vb;
  __shared__ __align__(16) short As[64][40], Ws[64][40];
  __shared__ __align__(16) short Tt[64][72];   // V transpose buffer [dim][key]
  const int tid = threadIdx.x, lane = tid & 63, wave = tid >> 6;
  const int col = lane & 15, quad = lane >> 4;
  const int wm = wave & 1, wn = wave >> 1;
  const int bm = blockIdx.x * 64, bn = blockIdx.y * 64;
  const f32x4 zero4 = {0.f, 0.f, 0.f, 0.f};
  f32x4 acc[2][2] = {{zero4, zero4}, {zero4, zero4}};
  const int row = tid >> 2, seg = tid & 3;
  for (int k0 = 0; k0 < D_; k0 += 32){
    __syncthreads();
    bf16x8 av = (bf16x8)(short)0;
    int gm = bm + row;
    if (gm < NF) av = *(const bf16x8*)(A + (long)gm * D_ + k0 + seg * 8);
    *(bf16x8*)&As[row][seg * 8] = av;
    *(bf16x8*)&Ws[row][seg * 8] = *(const bf16x8*)(W + (long)(bn + row) * D_ + k0 + seg * 8);
    __syncthreads();
    bf16x8 a0 = *(const bf16x8*)&As[wm * 32 + col][quad * 8];
    bf16x8 a1 = *(const bf16x8*)&As[wm * 32 + 16 + col][quad * 8];
    bf16x8 b0 = *(const bf16x8*)&Ws[wn * 32 + col][quad * 8];
    bf16x8 b1 = *(const bf16x8*)&Ws[wn * 32 + 16 + col][quad * 8];
    acc[0][0] = __builtin_amdgcn_mfma_f32_16x16x32_bf16(a0, b0, acc[0][0], 0, 0, 0);
    acc[0][1] = __builtin_amdgcn_mfma_f32_16x16x32_bf16(a0, b1, acc[0][1], 0, 0, 0);
    acc[1][0] = __builtin_amdgcn_mfma_f32_16x16x32_bf16(a1, b0, acc[1][0], 0, 0, 0);
    acc[1][1] = __builtin_amdgcn_mfma_f32_16x16x32_bf16(a1, b1, acc[1][1], 0, 0, 0);
  }
  if (z < 2){
    const float qscale = 0.25501133194822025f;  // (1/sqrt(32)) * log2e
    #pragma unroll
    for (int i = 0; i < 2; i++)
      #pragma unroll
      for (int j = 0; j < 2; j++)
        #pragma unroll
        for (int r = 0; r < 4; r++){
          int gm = bm + wm * 32 + i * 16 + quad * 4 + r;
          if (gm >= NF) continue;
          int gn = bn + wn * 32 + j * 16 + col;
          float v = acc[i][j][r] + bsp[gn];
          if (z == 0) v *= qscale;
          QKb[(long)z * NF * D_ + (long)gm * D_ + gn] = (short)f2b(v);
        }
  } else {
    // transpose tile into LDS: Tt[dim][key]; rows gm>=NF hold finite values
    #pragma unroll
    for (int i = 0; i < 2; i++)
      #pragma unroll
      for (int j = 0; j < 2; j++){
        int ln_ = wn * 32 + j * 16 + col;     // local dim
        int lc = wm * 32 + i * 16 + quad * 4; // local key base (4 consecutive)
        float bsv = bsp[bn + ln_];
        short pk[4];
        #pragma unroll
        for (int r = 0; r < 4; r++) pk[r] = (short)f2b(acc[i][j][r] + bsv);
        *(short4*)&Tt[ln_][lc] = *(short4*)pk;
      }
    __syncthreads();
    int lr = tid >> 2, sg = tid & 3;
    bf16x8 v0 = *(const bf16x8*)&Tt[lr][sg * 16];
    bf16x8 v1 = *(const bf16x8*)&Tt[lr][sg * 16 + 8];
    short* dstp = Vtg + (long)(bn + lr) * BSTRIDE + bm + sg * 16;
    *(bf16x8*)dstp = v0;
    *(bf16x8*)(dstp + 8) = v1;
  }
}

// ---- generic MFMA GEMM.
// MERGE=1: A[gm][k] = (sum_q Opart[q][k/32][gm][k%32]) / (sum_q Lpart[q][k/32][gm])
// ATOM=1: atomicAdd partial into Cf (bias added by z==0 block); else bf16 out + ACT.
template<int ACT, int ATOM, int MERGE>
__global__ __launch_bounds__(256) void mgemm(const short* __restrict__ A,
    const float* __restrict__ Op, const float* __restrict__ Lp,
    const short* __restrict__ W, const float* __restrict__ bs,
    float* __restrict__ Cf, short* __restrict__ Cb,
    int M, int Nn, int Kc, int Kstride){
  __shared__ __align__(16) short As[64][40], Ws[64][40];
  const int tid = threadIdx.x, lane = tid & 63, wave = tid >> 6;
  const int col = lane & 15, quad = lane >> 4;
  const int wm = wave & 1, wn = wave >> 1;
  const int bm = blockIdx.x * 64, bn = blockIdx.y * 64;
  const int koff = blockIdx.z * Kc;
  const f32x4 zero4 = {0.f, 0.f, 0.f, 0.f};
  f32x4 acc[2][2] = {{zero4, zero4}, {zero4, zero4}};
  const int row = tid >> 2, seg = tid & 3;
  for (int k0 = 0; k0 < Kc; k0 += 32){
    __syncthreads();
    int gm = bm + row;
    if (MERGE){
      int kg = koff + k0 + seg * 8;
      int hh = kg >> 5, d0 = kg & 31;
      short sarr[8] = {0,0,0,0,0,0,0,0};
      if (gm < M){
        float o0=0,o1=0,o2=0,o3=0,o4=0,o5=0,o6=0,o7=0, sl=0.f;
        #pragma unroll
        for (int q = 0; q < NSPLIT; q++){
          long rb = (long)(q * H_ + hh) * RPAD + gm;
          const float* op = Op + rb * HD_ + d0;
          float4 v0 = *(const float4*)op, v1 = *(const float4*)(op + 4);
          o0 += v0.x; o1 += v0.y; o2 += v0.z; o3 += v0.w;
          o4 += v1.x; o5 += v1.y; o6 += v1.z; o7 += v1.w;
          sl += Lp[rb];
        }
        float inv = 1.0f / sl;
        sarr[0]=(short)f2b(o0*inv); sarr[1]=(short)f2b(o1*inv);
        sarr[2]=(short)f2b(o2*inv); sarr[3]=(short)f2b(o3*inv);
        sarr[4]=(short)f2b(o4*inv); sarr[5]=(short)f2b(o5*inv);
        sarr[6]=(short)f2b(o6*inv); sarr[7]=(short)f2b(o7*inv);
      }
      *(bf16x8*)&As[row][seg * 8] = *(bf16x8*)sarr;
    } else {
      bf16x8 av = (bf16x8)(short)0;
      if (gm < M) av = *(const bf16x8*)(A + (long)gm * Kstride + koff + k0 + seg * 8);
      *(bf16x8*)&As[row][seg * 8] = av;
    }
    *(bf16x8*)&Ws[row][seg * 8] =
      *(const bf16x8*)(W + (long)(bn + row) * Kstride + koff + k0 + seg * 8);
    __syncthreads();
    bf16x8 a0 = *(const bf16x8*)&As[wm * 32 + col][quad * 8];
    bf16x8 a1 = *(const bf16x8*)&As[wm * 32 + 16 + col][quad * 8];
    bf16x8 b0 = *(const bf16x8*)&Ws[wn * 32 + col][quad * 8];
    bf16x8 b1 = *(const bf16x8*)&Ws[wn * 32 + 16 + col][quad * 8];
    acc[0][0] = __builtin_amdgcn_mfma_f32_16x16x32_bf16(a0, b0, acc[0][0], 0, 0, 0);
    acc[0][1] = __builtin_amdgcn_mfma_f32_16x16x32_bf16(a0, b1, acc[0][1], 0, 0, 0);
    acc[1][0] = __builtin_amdgcn_mfma_f32_16x16x32_bf16(a1, b0, acc[1][0], 0, 0, 0);
    acc[1][1] = __builtin_amdgcn_mfma_f32_16x16x32_bf16(a1, b1, acc[1][1], 0, 0, 0);
  }
  #pragma unroll
  for (int i = 0; i < 2; i++)
    #pragma unroll
    for (int j = 0; j < 2; j++)
      #pragma unroll
      for (int r = 0; r < 4; r++){
        int gm = bm + wm * 32 + i * 16 + quad * 4 + r;
        if (gm >= M) continue;
        int gn = bn + wn * 32 + j * 16 + col;
        if (ATOM){
          float v = acc[i][j][r] + (blockIdx.z == 0 ? bs[gn] : 0.f);
          atomicAdd(&Cf[(long)gm * Nn + gn], v);
        } else {
          float v = acc[i][j][r] + bs[gn];
          if (ACT == 1) v = v * 0.5f * (1.0f + erff(v * 0.70710678118654752f));
          Cb[(long)gm * Nn + gn] = (short)f2b(v);
        }
      }
}

// ---- flash attention, fixed-shift softmax in exp2 domain.
// grid (33, H, NSPLIT); block = 4 waves x 16 rows.
// Key permutation: MFMA sub-tile t4 covers key j0 + col*4 + t4, so each lane's
// 4 bias bytes per row are ONE coalesced global dword, and P is written with
// packed ds_write_b64.
__global__ __launch_bounds__(256) void fattn_k(const short* __restrict__ Qb,
    const short* __restrict__ Kb, const short* __restrict__ Vtg,
    const unsigned char* __restrict__ bias8, float* __restrict__ Opart,
    float* __restrict__ Lpart){
  __shared__ __align__(16) short Ks[64][42];   // stride 42: 2-way max on permuted reads
  __shared__ __align__(16) short Vt[32][72];
  __shared__ __align__(16) short Ps[4][16][72];

  const int tid = threadIdx.x, wave = tid >> 6, lane = tid & 63;
  const int col = lane & 15, quad = lane >> 4;
  const int h = blockIdx.y, qz = blockIdx.z;
  const int i0 = blockIdx.x * 64 + wave * 16;
  const int t0 = (qz == 0) ? 0 : 9 + 8 * (qz - 1);   // 0,9,17,25
  const int t1 = t0 + ((qz == 0) ? 9 : 8);           // 33 tiles total

  int qrow = min(i0 + col, NF - 1);
  bf16x8 qf = *(const bf16x8*)(Qb + (long)qrow * D_ + h * HD_ + quad * 8);

  int brow[4];
  #pragma unroll
  for (int r = 0; r < 4; r++) brow[r] = min(i0 + quad * 4 + r, NF - 1);

  f32x4 oacc0 = {0.f, 0.f, 0.f, 0.f}, oacc1 = {0.f, 0.f, 0.f, 0.f};
  float rs[4] = {0.f, 0.f, 0.f, 0.f};
  const f32x4 zero4 = {0.f, 0.f, 0.f, 0.f};
  short* Pp = &Ps[wave][0][0];

  for (int t = t0; t < t1; t++){
    const int j0 = t * 64;
    // bias: one dword per row (4 fp8 bytes for t4=0..3), coalesced across col
    unsigned bw[4];
    #pragma unroll
    for (int r = 0; r < 4; r++)
      bw[r] = *(const unsigned*)(bias8 + (long)(h * NF + brow[r]) * BSTRIDE + j0 + col * 4);
    __syncthreads();
    { // K tile: 64 keys x 32 dims
      int key = tid >> 2, seg = tid & 3;
      int j = j0 + key;
      bf16x8 kv = (bf16x8)(short)0;
      if (j < NF) kv = *(const bf16x8*)(Kb + (long)j * D_ + h * HD_ + seg * 8);
      *(bf16x8*)&Ks[key][seg * 8] = kv;
    }
    { // V tile (pre-transposed): 32 dims x 64 keys
      int d = tid >> 3, seg = tid & 7;
      *(bf16x8*)&Vt[d][seg * 8] =
        *(const bf16x8*)(Vtg + (long)(h * HD_ + d) * BSTRIDE + j0 + seg * 8);
    }
    __syncthreads();

    f32x4 sacc[4];
    #pragma unroll
    for (int t4 = 0; t4 < 4; t4++){
      bf16x8 kf = *(const bf16x8*)&Ks[col * 4 + t4][quad * 8];
      sacc[t4] = __builtin_amdgcn_mfma_f32_16x16x32_bf16(qf, kf, zero4, 0, 0, 0);
    }

    const bool tail = (j0 + 64 > NF);
    #pragma unroll
    for (int r = 0; r < 4; r++){
      // fp8 byte-select must be a literal: decode all 4 bytes explicitly
      float bv0 = __builtin_amdgcn_cvt_f32_fp8((int)bw[r], 0);
      float bv1 = __builtin_amdgcn_cvt_f32_fp8((int)bw[r], 1);
      float bv2 = __builtin_amdgcn_cvt_f32_fp8((int)bw[r], 2);
      float bv3 = __builtin_amdgcn_cvt_f32_fp8((int)bw[r], 3);
      float bvv[4] = {bv0, bv1, bv2, bv3};
      unsigned short pb[4];
      #pragma unroll
      for (int t4 = 0; t4 < 4; t4++){
        float p = exp2f(sacc[t4][r] + bvv[t4]);   // Q pre-scaled by scale*log2e
        if (tail && (j0 + col * 4 + t4 >= NF)) p = 0.f;
        unsigned pu = __float_as_uint(p) & 0xffff0000u;  // RTZ to bf16
        rs[r] += __uint_as_float(pu);                    // consistent with PV
        pb[t4] = (unsigned short)(pu >> 16);
      }
      unsigned u0 = (unsigned)pb[0] | ((unsigned)pb[1] << 16);
      unsigned u1 = (unsigned)pb[2] | ((unsigned)pb[3] << 16);
      *(uint2*)&Pp[(quad * 4 + r) * 72 + col * 4] = make_uint2(u0, u1);
    }

    #pragma unroll
    for (int ks = 0; ks < 2; ks++){
      bf16x8 af = *(const bf16x8*)&Pp[col * 72 + ks * 32 + quad * 8];
      bf16x8 v0 = *(const bf16x8*)&Vt[col][ks * 32 + quad * 8];
      bf16x8 v1 = *(const bf16x8*)&Vt[16 + col][ks * 32 + quad * 8];
      oacc0 = __builtin_amdgcn_mfma_f32_16x16x32_bf16(af, v0, oacc0, 0, 0, 0);
      oacc1 = __builtin_amdgcn_mfma_f32_16x16x32_bf16(af, v1, oacc1, 0, 0, 0);
    }
  }

  #pragma unroll
  for (int r = 0; r < 4; r++){
    #pragma unroll
    for (int o = 1; o < 16; o <<= 1) rs[r] += __shfl_xor(rs[r], o, 64);
  }
  long pi = ((long)qz * H_ + h) * RPAD + i0 + quad * 4;
  #pragma unroll
  for (int r = 0; r < 4; r++){
    Opart[(pi + r) * HD_ + col] = oacc0[r];
    Opart[(pi + r) * HD_ + 16 + col] = oacc1[r];
    if (col == 0) Lpart[pi + r] = rs[r];
  }
}

extern "C" void kernel_launch(void* const* d_in, const int* in_sizes, int n_in,
                              void* d_out, int out_size, void* d_ws, size_t ws_size,
                              hipStream_t stream){
  const float* x    = (const float*)d_in[0];
  const float* ea   = (const float*)d_in[1];
  const float* npw  = (const float*)d_in[2];
  const float* npb  = (const float*)d_in[3];
  const float* inE  = (const float*)d_in[4];
  const float* outE = (const float*)d_in[5];
  const float* db   = (const float*)d_in[6];
  const float* epw  = (const float*)d_in[7];
  const float* epb  = (const float*)d_in[8];
  const float* cls  = (const float*)d_in[9];
  const float* qw   = (const float*)d_in[10];
  const float* qb   = (const float*)d_in[11];
  const float* kw   = (const float*)d_in[12];
  const float* kb   = (const float*)d_in[13];
  const float* vw   = (const float*)d_in[14];
  const float* vb   = (const float*)d_in[15];
  const float* ow   = (const float*)d_in[16];
  const float* ob   = (const float*)d_in[17];
  const float* f1w  = (const float*)d_in[18];
  const float* f1b  = (const float*)d_in[19];
  const float* f2w  = (const float*)d_in[20];
  const float* f2bp = (const float*)d_in[21];
  const float* ln1s = (const float*)d_in[22];
  const float* ln1b = (const float*)d_in[23];
  const float* ln2s = (const float*)d_in[24];
  const float* ln2b = (const float*)d_in[25];
  const float* fns  = (const float*)d_in[26];
  const float* fnb  = (const float*)d_in[27];
  const int*   ei   = (const int*)d_in[28];
  const int*   dist = (const int*)d_in[29];

  float* ws = (float*)d_ws;
  long off = 0;
  float* h     = ws + off; off += (long)NF * D_;
  float* Opart = ws + off; off += (long)NSPLIT * H_ * RPAD * HD_;
  float* Lpart = ws + off; off += (long)NSPLIT * H_ * RPAD;
  unsigned char* bias8 = (unsigned char*)(ws + off);
  off += ((long)H_ * NF * BSTRIDE + 3) / 4;
  short* hnb   = (short*)(ws + off); off += ((long)NF * D_ + 1) / 2;
  short* QKb   = (short*)(ws + off); off += (long)NF * D_;      // Q then K
  short* Vtg   = (short*)(ws + off); off += ((long)D_ * BSTRIDE + 1) / 2;
  short* midb  = (short*)(ws + off); off += ((long)NF * FFN_ + 1) / 2;
  short* wqkv  = (short*)(ws + off); off += ((long)3 * L_ * D_ * D_ + 1) / 2;
  short* owb   = (short*)(ws + off); off += ((long)L_ * D_ * D_ + 1) / 2;
  short* f1wb  = (short*)(ws + off); off += ((long)L_ * FFN_ * D_ + 1) / 2;
  short* f2wb  = (short*)(ws + off); off += ((long)L_ * FFN_ * D_ + 1) / 2;
  int*   ind   = (int*)(ws + off);
  int*   outd  = ind + N_;

  zero_int<<<(2 * N_ + 255) / 256, 256, 0, stream>>>(ind, 2 * N_);
  deg_count<<<(E_ + 255) / 256, 256, 0, stream>>>(ei, ind, outd);
  embed_k<<<NF, D_, 0, stream>>>(x, npw, npb, inE, outE, ind, outd, cls, h);
  bias_fill<<<NF, 256, 0, stream>>>(dist, db, bias8);
  edge_bias<<<(E_ + 255) / 256, 256, 0, stream>>>(ea, epw, epb, ei, bias8);
  {
    long LFD = (long)L_ * FFN_ * D_;
    w2b_all<<<(int)((LFD + 255) / 256), 256, 0, stream>>>(qw, kw, vw, ow, f1w, f2w,
                                                          wqkv, owb, f1wb, f2wb);
  }

  dim3 gQKV((NF + 63) / 64, D_ / 64, 3);
  dim3 gO((NF + 63) / 64, D_ / 64, 2);
  dim3 gF((NF + 63) / 64, FFN_ / 64, 1);
  dim3 gF2((NF + 63) / 64, D_ / 64, 4);
  dim3 gA((NF + 63) / 64, H_, NSPLIT);
  for (int l = 0; l < L_; l++){
    ln_k<<<NF, D_, 0, stream>>>(h, ln1s + l * D_, ln1b + l * D_, nullptr, hnb, 0);
    qkv_gemm<<<gQKV, 256, 0, stream>>>(hnb, wqkv, qb + l * D_, kb + l * D_, vb + l * D_,
                                       QKb, Vtg, l);
    fattn_k<<<gA, 256, 0, stream>>>(QKb, QKb + (long)NF * D_, Vtg, bias8, Opart, Lpart);
    mgemm<0,1,1><<<gO, 256, 0, stream>>>(nullptr, Opart, Lpart,
                                         owb + (long)l * D_ * D_, ob + l * D_,
                                         h, nullptr, NF, D_, 128, D_);
    ln_k<<<NF, D_, 0, stream>>>(h, ln2s + l * D_, ln2b + l * D_, nullptr, hnb, 0);
    mgemm<1,0,0><<<gF, 256, 0, stream>>>(hnb, nullptr, nullptr,
                                         f1wb + (long)l * FFN_ * D_, f1b + l * FFN_,
                                         nullptr, midb, NF, FFN_, D_, D_);
    mgemm<0,1,0><<<gF2, 256, 0, stream>>>(midb, nullptr, nullptr,
                                          f2wb + (long)l * FFN_ * D_, f2bp + l * D_,
                                          h, nullptr, NF, D_, 256, FFN_);
  }
  ln_k<<<NF, D_, 0, stream>>>(h, fns, fnb, (float*)d_out, nullptr, 1);
}